// Round 4
// baseline (1015.054 us; speedup 1.0000x reference)
//
#include <hip/hip_runtime.h>
#include <hip/hip_bf16.h>

// R4 = R3 resubmit (R3 bench died: "container failed twice", no counters — infra-flake
// theory; source re-audited for OOB/hang, none found).
// R3 theory: LDS-BW + VALU co-bound (VALU 47%, MFMA 22%, ~1.3MB LDS traffic/block).
// 1) Phase 1 -> mfma_32x32x16 (2x MACs per LDS byte): 960->576 KB/block fragment reads.
// 2) Fragment-linear ws images: every phase-1 ds_read_b128 is base+lane*16 (linear,
//    conflict-free, no address VALU). Rows 66..95 zero-padded.
// 3) presplit_x LDS-staged: coalesced reads AND coalesced 16B fragment stores.
// Predicted: main 735->~590us, pre ~120us, MfmaUtil ~27%, conflicts ~1.6e7.

constexpr int T  = 6;
constexpr int S  = 66;    // 3*J
constexpr int IN = 256;
constexpr int H  = 8;
constexpr int D  = 32;
constexpr int J  = 22;
constexpr float NEG = -9e15f;
constexpr float INV_SQRT_D = 0.17677669529663688110f; // 1/sqrt(32)

// ---------------- LDS map (bytes), SMEM 50,008 -> 3 blocks/CU (<=53,248) -------------
// proj stage (per 64-K chunk, x4): x frags [12 hi | 12 lo]x1KB @0; W frags @24,576
//   (end 49,152). Fragment-linear: tile(mtile|mat,ks)*1KB + lane*16.
// attn persistent:
//   qh/ql bf16[66][36] @0/4,752     kh/kl @9,504/14,256 (end 19,008)
//   sc f32[66][66] @19,008 (end 36,432)
//   vTh/vTl bf16[32][104] @36,432/43,088 (208B rows, end 49,744)
//   inv f32[66] @49,744 (end 50,008)
// softmax->PV overlays: Ph/Pl bf16[66][104] @0/13,728 (end 27,456); aoT bf16[32][104] @27,456
// phase-6 overlays (vT dead): Wch/Wcl bf16[32][104] @36,432/43,088
#define XH_OFF   0
#define WH_OFF   24576
#define FRAG_LO  12288
#define QH_OFF   0
#define QL_OFF   4752
#define KH_OFF   9504
#define KL_OFF   14256
#define SC_OFF   19008
#define VTH_OFF  36432
#define VTL_OFF  43088
#define INV_OFF  49744
#define PH_OFF   0
#define PL_OFF   13728
#define AOT_OFF  27456
#define WCH_OFF  36432
#define WCL_OFF  43088
#define SMEM_BYTES 50008

// ws layout: 32 W images (h*4+chunk) of [12 hi-frag | 12 lo-frag]x1KB = 24,576 -> 786,432;
// Wc image [hi 32x208B | lo 32x208B] = 13,312 -> end 799,744;
// x images: per bt (3072): 4 chunks x 24,576 fragment-linear = 98,304 -> ~303 MB total.
#define WSW_STRIDE 24576
#define WSWC_OFF   786432
#define WS_W       799744ull
#define XIMG_OFF   799744
#define XIMG_BT    98304
#define WS_FULL    (799744ull + 3072ull * 98304ull)

typedef float f32x4   __attribute__((ext_vector_type(4)));
typedef float f32x16  __attribute__((ext_vector_type(16)));
typedef short bf16x8  __attribute__((ext_vector_type(8)));
typedef short s4v     __attribute__((ext_vector_type(4)));

__device__ __forceinline__ unsigned cvtpk(float a, float b) {
    unsigned r;
    asm("v_cvt_pk_bf16_f32 %0, %1, %2" : "=v"(r) : "v"(a), "v"(b));
    return r;   // low16 = bf16(a), high16 = bf16(b), RNE
}
__device__ __forceinline__ float bfh2f(unsigned short h) {
    return __uint_as_float(((unsigned)h) << 16);
}
// split two f32 into packed bf16 hi (rne) and bf16 lo (rne of residual) — 6 VALU
__device__ __forceinline__ void split2(float a, float b, unsigned& hi, unsigned& lo) {
    unsigned h = cvtpk(a, b);
    float ra = a - __uint_as_float(h << 16);
    float rb = b - __uint_as_float(h & 0xffff0000u);
    lo = cvtpk(ra, rb);
    hi = h;
}
// load 8 bf16 from an 8-byte-aligned LDS address as two b64 reads
__device__ __forceinline__ bf16x8 ld_bf16x8_a8(const short* p) {
    s4v a = *(const s4v*)p;
    s4v b = *(const s4v*)(p + 4);
    return __builtin_shufflevector(a, b, 0, 1, 2, 3, 4, 5, 6, 7);
}
// async global->LDS, 16B/lane; lds base wave-uniform (HW adds lane*16)
__device__ __forceinline__ void gload16(const void* g, void* l) {
    __builtin_amdgcn_global_load_lds(
        (const __attribute__((address_space(1))) unsigned*)g,
        (__attribute__((address_space(3))) unsigned*)l, 16, 0, 0);
}

// ---------------- pre-kernel: W(h,chunk) fragment images + Wc image ------------------
__global__ __launch_bounds__(256)
void presplit_kernel(const float* __restrict__ Wq, const float* __restrict__ Wk,
                     const float* __restrict__ Wv, const float* __restrict__ Wc,
                     unsigned char* __restrict__ ws)
{
    int gid = blockIdx.x * 256 + threadIdx.x;
    if (gid < 49152) {                     // 32 images x 96 rows x 16 col-groups
        int img = gid / 1536, u = gid - img * 1536;
        int row = u >> 4, c = u & 15, k0 = c << 2;
        int mat = row >> 5, dd = row & 31;
        int chunk = img & 3, hh = img >> 2;
        const float* Wm = (mat == 0) ? Wq : (mat == 1) ? Wk : Wv;
        float4 v = *(const float4*)(Wm + (size_t)(hh * 32 + dd) * IN + chunk * 64 + c * 4);
        uint2 hi, lo;
        split2(v.x, v.y, hi.x, lo.x);
        split2(v.z, v.w, hi.y, lo.y);
        // fragment position: tile(mat,ks), lane = col + 32*khalf, elem byte = (k0&7)*2
        int tile  = (mat << 2) + (k0 >> 4);
        int lanei = dd + (((k0 >> 3) & 1) << 5);
        int byte  = (tile << 10) + (lanei << 4) + ((k0 & 7) << 1);
        unsigned char* base = ws + (size_t)img * WSW_STRIDE;
        *(uint2*)(base + byte)           = hi;
        *(uint2*)(base + FRAG_LO + byte) = lo;
    } else if (gid < 49152 + 1664) {       // Wc image: 32 rows x 52 dword cols (zero-padded)
        int g2  = gid - 49152;
        int row = g2 / 52, cu = g2 - row * 52;
        int c0  = 2 * cu;
        float a = (row < 22 && c0     < 66) ? Wc[row * 66 + c0]     : 0.f;
        float b = (row < 22 && c0 + 1 < 66) ? Wc[row * 66 + c0 + 1] : 0.f;
        unsigned hi, lo;
        split2(a, b, hi, lo);
        *(unsigned*)(ws + WSWC_OFF + row * 208 + 4 * cu)        = hi;
        *(unsigned*)(ws + WSWC_OFF + 6656 + row * 208 + 4 * cu) = lo;
    }
}

// ---------------- pre-kernel: x -> fragment-linear images, LDS-staged ----------------
// One block per (bt, chunk): coalesced float4 reads -> LDS [96][128B] hi/lo (rows
// 66..95 zeroed) -> each wave emits 6 x 1KB fragment tiles as coalesced 16B stores.
__global__ __launch_bounds__(256)
void presplit_x_kernel(const float* __restrict__ x, unsigned char* __restrict__ ws)
{
    __shared__ __align__(16) unsigned char lds[24576];
    const int tid = threadIdx.x;
    const int chunk = blockIdx.x & 3;
    const int bt = blockIdx.x >> 2;
    const float* xg = x + (size_t)bt * S * IN + chunk * 64;
    for (int u = tid; u < 1536; u += 256) {
        int s = u >> 4, c = u & 15;
        int rel = ((s << 7) + (c << 3)) ^ ((s & 7) << 4);
        uint2 hi = {0u, 0u}, lo = {0u, 0u};
        if (s < 66) {
            float4 v = *(const float4*)(xg + (size_t)s * IN + c * 4);
            split2(v.x, v.y, hi.x, lo.x);
            split2(v.z, v.w, hi.y, lo.y);
        }
        *(uint2*)(lds + rel)         = hi;
        *(uint2*)(lds + 12288 + rel) = lo;
    }
    __syncthreads();
    const int lane = tid & 63, wid = tid >> 6;
    unsigned char* img = ws + XIMG_OFF + (size_t)bt * XIMG_BT + chunk * 24576;
    for (int i = wid; i < 24; i += 4) {
        int comp = (i >= 12) ? 1 : 0;
        int ti = i - comp * 12;
        int mtile = ti >> 2, ks = ti & 3;
        int row = mtile * 32 + (lane & 31);
        int rel = ((row << 7) + (ks << 5) + ((lane >> 5) << 4)) ^ ((row & 7) << 4);
        uint4 v = *(const uint4*)(lds + comp * 12288 + rel);
        *(uint4*)(img + (i << 10) + (lane << 4)) = v;
    }
}

// MODE: 0 = all inline, 1 = W/Wc presplit, 2 = W/Wc + x presplit
template<int MODE>
__global__ __launch_bounds__(256, 3)
void mha_fused_kernel(const float* __restrict__ x,
                      const float* __restrict__ Wq, const float* __restrict__ bq,
                      const float* __restrict__ Wk, const float* __restrict__ bk,
                      const float* __restrict__ Wv, const float* __restrict__ bv,
                      const float* __restrict__ Wc, const float* __restrict__ bc,
                      const unsigned char* __restrict__ ws,
                      float* __restrict__ out)
{
    __shared__ __align__(16) unsigned char smem[SMEM_BYTES];

    const int tid = threadIdx.x;
    // bt-grouping XCD swizzle: 8 heads of one bt land on one XCD, adjacent in time.
    const int i0  = blockIdx.x;
    const int h   = (i0 >> 3) & 7;
    const int bt  = (i0 & 7) | ((i0 >> 6) << 3);   // bijective over [0,3072)

    const int wid  = tid >> 6;           // wave 0..3
    const int lane = tid & 63;
    const int l15  = lane & 15;
    const int quad = lane >> 4;

    // ---------------- Phase 1: q,k,v projections via split-bf16 32x32x16 MFMA --------
    const f32x16 zacc = {0.f,0.f,0.f,0.f,0.f,0.f,0.f,0.f,0.f,0.f,0.f,0.f,0.f,0.f,0.f,0.f};
    f32x16 accs[3] = {zacc, zacc, zacc};

    for (int chunk = 0; chunk < 4; ++chunk) {    // K = 4 x 64
        __syncthreads();
        if constexpr (MODE == 2) {
            const unsigned char* ximg = ws + XIMG_OFF + (size_t)bt * XIMG_BT + chunk * 24576;
            const unsigned char* wimg = ws + (size_t)((h << 2) | chunk) * WSW_STRIDE;
            for (int i = wid; i < 24; i += 4)
                gload16(ximg + (i << 10) + (lane << 4), smem + XH_OFF + (i << 10));
            for (int i = wid; i < 24; i += 4)
                gload16(wimg + (i << 10) + (lane << 4), smem + WH_OFF + (i << 10));
        } else {
            if constexpr (MODE == 1) {
                const unsigned char* wimg = ws + (size_t)((h << 2) | chunk) * WSW_STRIDE;
                for (int i = wid; i < 24; i += 4)
                    gload16(wimg + (i << 10) + (lane << 4), smem + WH_OFF + (i << 10));
            } else {
                for (int u = tid; u < 1536; u += 256) {   // W inline -> fragment-linear
                    int row = u >> 4, c = u & 15, k0 = c << 2;
                    int mat = row >> 5, dd2 = row & 31;
                    const float* Wm = (mat == 0) ? Wq : (mat == 1) ? Wk : Wv;
                    float4 v = *(const float4*)(Wm + (size_t)(h * 32 + dd2) * IN + chunk * 64 + c * 4);
                    uint2 hi, lo;
                    split2(v.x, v.y, hi.x, lo.x);
                    split2(v.z, v.w, hi.y, lo.y);
                    int tile  = (mat << 2) + (k0 >> 4);
                    int lanei = dd2 + (((k0 >> 3) & 1) << 5);
                    int byte  = (tile << 10) + (lanei << 4) + ((k0 & 7) << 1);
                    *(uint2*)(smem + WH_OFF + byte)           = hi;
                    *(uint2*)(smem + WH_OFF + FRAG_LO + byte) = lo;
                }
            }
            const float* xg = x + (size_t)bt * S * IN + chunk * 64;
            for (int u = tid; u < 1536; u += 256) {       // x inline -> fragment-linear
                int s = u >> 4, c = u & 15, k0 = c << 2;
                uint2 hi = {0u, 0u}, lo = {0u, 0u};
                if (s < 66) {
                    float4 v = *(const float4*)(xg + (size_t)s * IN + c * 4);
                    split2(v.x, v.y, hi.x, lo.x);
                    split2(v.z, v.w, hi.y, lo.y);
                }
                int tile  = ((s >> 5) << 2) + (k0 >> 4);
                int lanei = (s & 31) + (((k0 >> 3) & 1) << 5);
                int byte  = (tile << 10) + (lanei << 4) + ((k0 & 7) << 1);
                *(uint2*)(smem + XH_OFF + byte)           = hi;
                *(uint2*)(smem + XH_OFF + FRAG_LO + byte) = lo;
            }
        }
        __syncthreads();

        #pragma unroll
        for (int t = 0; t < 3; ++t) {
            int p = wid + 4 * t;                 // p = mtile*3 + mat, over [0,9)
            if (p >= 9) break;                   // wave-uniform
            int mtile = p / 3, mat = p - mtile * 3;
            const unsigned char* xa = smem + XH_OFF + ((mtile * 4) << 10) + (lane << 4);
            const unsigned char* wb = smem + WH_OFF + ((mat   * 4) << 10) + (lane << 4);
            #pragma unroll
            for (int ks = 0; ks < 4; ++ks) {
                bf16x8 ah = *(const bf16x8*)(xa + (ks << 10));
                bf16x8 al = *(const bf16x8*)(xa + (ks << 10) + FRAG_LO);
                bf16x8 bh = *(const bf16x8*)(wb + (ks << 10));
                bf16x8 bl = *(const bf16x8*)(wb + (ks << 10) + FRAG_LO);
                accs[t] = __builtin_amdgcn_mfma_f32_32x32x16_bf16(ah, bh, accs[t], 0, 0, 0);
                accs[t] = __builtin_amdgcn_mfma_f32_32x32x16_bf16(ah, bl, accs[t], 0, 0, 0);
                accs[t] = __builtin_amdgcn_mfma_f32_32x32x16_bf16(al, bh, accs[t], 0, 0, 0);
            }
        }
    }
    __syncthreads();   // stage dead; epilogue overwrites it

    // -------- Epilogue: q/k -> hi/lo [s][d]; v -> relu, hi/lo transposed [d][s] ------
    // 32x32 C/D layout: col = lane&31, row = (reg&3) + 8*(reg>>2) + 4*(lane>>5).
    {
        short* qh = (short*)(smem + QH_OFF); short* ql = (short*)(smem + QL_OFF);
        short* kh = (short*)(smem + KH_OFF); short* kl = (short*)(smem + KL_OFF);
        const int dd = lane & 31;
        const int half = lane >> 5;
        #pragma unroll
        for (int t = 0; t < 3; ++t) {
            int p = wid + 4 * t;
            if (p >= 9) break;
            int mtile = p / 3, mat = p - mtile * 3;
            const float* bias_p = (mat == 0) ? bq : (mat == 1) ? bk : bv;
            float bias = bias_p[h * 32 + dd];
            if (mat < 2) {
                short* bh_ = (mat == 0) ? qh : kh;
                short* bl_ = (mat == 0) ? ql : kl;
                #pragma unroll
                for (int g = 0; g < 4; ++g) {
                    int sb2 = mtile * 32 + half * 4 + 8 * g;
                    uint2 hi, lo;
                    split2(accs[t][4*g+0] + bias, accs[t][4*g+1] + bias, hi.x, lo.x);
                    split2(accs[t][4*g+2] + bias, accs[t][4*g+3] + bias, hi.y, lo.y);
                    unsigned hs[4] = { hi.x & 0xffffu, hi.x >> 16, hi.y & 0xffffu, hi.y >> 16 };
                    unsigned ls[4] = { lo.x & 0xffffu, lo.x >> 16, lo.y & 0xffffu, lo.y >> 16 };
                    #pragma unroll
                    for (int r = 0; r < 4; ++r) {
                        int s = sb2 + r;
                        if (s < 66) {
                            bh_[s * 36 + dd] = (short)hs[r];
                            bl_[s * 36 + dd] = (short)ls[r];
                        }
                    }
                }
            } else {
                #pragma unroll
                for (int g = 0; g < 4; ++g) {
                    int sb2 = mtile * 32 + half * 4 + 8 * g;
                    float vv[4];
                    #pragma unroll
                    for (int r = 0; r < 4; ++r) {
                        int s = sb2 + r;
                        vv[r] = (s < 66) ? fmaxf(accs[t][4*g+r] + bias, 0.f) : 0.f; // zero pad
                    }
                    uint2 ph, pl;
                    split2(vv[0], vv[1], ph.x, pl.x);
                    split2(vv[2], vv[3], ph.y, pl.y);
                    *(uint2*)(smem + VTH_OFF + dd * 208 + 2 * sb2) = ph;
                    *(uint2*)(smem + VTL_OFF + dd * 208 + 2 * sb2) = pl;
                }
            }
        }
        // vT rows fully cover s 0..95 (zeros beyond 66) — no separate zero loop needed.
    }
    __syncthreads();

    // ---------------- Phase 3: sc = mask * (q k^T) / sqrt(D) via split MFMA ----------
    {
        const short* qh = (const short*)(smem + QH_OFF);
        const short* ql = (const short*)(smem + QL_OFF);
        const short* kh = (const short*)(smem + KH_OFF);
        const short* kl = (const short*)(smem + KL_OFF);
        float* sc = (float*)(smem + SC_OFF);
        for (int t = 0; t < 7; ++t) {
            int tt = wid + 4 * t;
            if (tt >= 25) break;                 // wave-uniform
            int mq = tt / 5, mk = tt - mq * 5;
            int aoff = (mq * 16 + l15) * 36 + quad * 8;
            int boff = (mk * 16 + l15) * 36 + quad * 8;
            bf16x8 ah = ld_bf16x8_a8(qh + aoff);
            bf16x8 al = ld_bf16x8_a8(ql + aoff);
            bf16x8 bh = ld_bf16x8_a8(kh + boff);
            bf16x8 bl = ld_bf16x8_a8(kl + boff);
            f32x4 acc = (f32x4){0.f, 0.f, 0.f, 0.f};
            acc = __builtin_amdgcn_mfma_f32_16x16x32_bf16(ah, bh, acc, 0, 0, 0);
            acc = __builtin_amdgcn_mfma_f32_16x16x32_bf16(ah, bl, acc, 0, 0, 0);
            acc = __builtin_amdgcn_mfma_f32_16x16x32_bf16(al, bh, acc, 0, 0, 0);
            int ks = mk * 16 + l15;
            #pragma unroll
            for (int reg = 0; reg < 4; ++reg) {
                int qs = mq * 16 + quad * 4 + reg;
                if (qs < 66 && ks < 66) {
                    bool masked = (qs < J && ks >= 2 * J) || (qs >= 2 * J && ks < J);
                    sc[qs * 66 + ks] = masked ? 0.f : acc[reg] * INV_SQRT_D;
                }
            }
        }
    }
    __syncthreads();

    // ---------------- Phase 4: prune + softmax (16-lane groups, regs + shuffles) ------
    // Group->row remap: rows step by 4 within a wave -> sc reads land on banks {0,8,16,24}.
    {
        const float* sc = (const float*)(smem + SC_OFF);
        const int group = tid >> 4, lane16 = tid & 15;
        const int rbase = ((group & 3) << 2) + (group >> 2);   // bijection over [0,16)
        float val[5][5];
        #pragma unroll
        for (int i = 0; i < 5; ++i) {
            int r = rbase + 16 * i;
            #pragma unroll
            for (int tt = 0; tt < 5; ++tt) {
                int c = lane16 + 16 * tt;
                val[i][tt] = (r < 66 && c < 66) ? sc[r * 66 + c] : -INFINITY;
            }
        }
        __syncthreads();   // all sc reads done -> P may overlay sc front

        short* Ph = (short*)(smem + PH_OFF);
        short* Pl = (short*)(smem + PL_OFF);
        float* inv = (float*)(smem + INV_OFF);
        #pragma unroll
        for (int i = 0; i < 5; ++i) {
            int r = rbase + 16 * i;
            if (r >= 66) continue;               // group-uniform
            float m = -INFINITY;
            #pragma unroll
            for (int tt = 0; tt < 5; ++tt) m = fmaxf(m, val[i][tt]);
            m = fmaxf(m, __shfl_xor(m, 1));
            m = fmaxf(m, __shfl_xor(m, 2));
            m = fmaxf(m, __shfl_xor(m, 4));
            m = fmaxf(m, __shfl_xor(m, 8));
            const float thr = m / 9.0f;
            float e[5], lsum = 0.f, rmax = -INFINITY;
            #pragma unroll
            for (int tt = 0; tt < 5; ++tt) {
                float sv = val[i][tt];
                float pr = (fabsf(sv) <= thr) ? NEG : sv;   // -INF sentinels stay below
                val[i][tt] = pr;
                rmax = fmaxf(rmax, pr);
            }
            rmax = fmaxf(rmax, __shfl_xor(rmax, 1));
            rmax = fmaxf(rmax, __shfl_xor(rmax, 2));
            rmax = fmaxf(rmax, __shfl_xor(rmax, 4));
            rmax = fmaxf(rmax, __shfl_xor(rmax, 8));
            #pragma unroll
            for (int tt = 0; tt < 5; ++tt) {
                int c = lane16 + 16 * tt;
                float ev = (c < 66) ? __expf(val[i][tt] - rmax) : 0.f;
                e[tt] = ev;
                lsum += ev;
            }
            lsum += __shfl_xor(lsum, 1);
            lsum += __shfl_xor(lsum, 2);
            lsum += __shfl_xor(lsum, 4);
            lsum += __shfl_xor(lsum, 8);
            #pragma unroll
            for (int tt = 0; tt < 6; ++tt) {     // cols 0..95: data or zero pad
                int c = lane16 + 16 * tt;
                unsigned short hi = 0, lo = 0;
                if (c < 66) {
                    float ev = e[tt];
                    hi = (unsigned short)cvtpk(ev, ev);
                    lo = (unsigned short)cvtpk(ev - bfh2f(hi), 0.f);
                }
                if (c < 96) {
                    Ph[r * 104 + c] = (short)hi;
                    Pl[r * 104 + c] = (short)lo;
                }
            }
            if (lane16 == 0) inv[r] = 1.0f / lsum;
        }
    }
    __syncthreads();

    // ---------------- Phase 5: aoT = (P @ v)^T * inv, bf16-hi, via MFMA --------------
    {
        const short* Ph = (const short*)(smem + PH_OFF);
        const short* Pl = (const short*)(smem + PL_OFF);
        const short* vh = (const short*)(smem + VTH_OFF);
        const short* vl = (const short*)(smem + VTL_OFF);
        const float* inv = (const float*)(smem + INV_OFF);
        for (int t = 0; t < 3; ++t) {
            int tt = wid + 4 * t;
            if (tt >= 10) break;
            int mq = tt >> 1, nd = tt & 1;
            f32x4 acc = (f32x4){0.f, 0.f, 0.f, 0.f};
            #pragma unroll
            for (int ks = 0; ks < 3; ++ks) {
                bf16x8 a   = *(const bf16x8*)(Ph + (mq * 16 + l15) * 104 + ks * 32 + quad * 8);
                bf16x8 al8 = *(const bf16x8*)(Pl + (mq * 16 + l15) * 104 + ks * 32 + quad * 8);
                bf16x8 b   = *(const bf16x8*)(vh + (nd * 16 + l15) * 104 + ks * 32 + quad * 8);
                bf16x8 bl8 = *(const bf16x8*)(vl + (nd * 16 + l15) * 104 + ks * 32 + quad * 8);
                acc = __builtin_amdgcn_mfma_f32_16x16x32_bf16(a, b, acc, 0, 0, 0);
                acc = __builtin_amdgcn_mfma_f32_16x16x32_bf16(al8, b, acc, 0, 0, 0);
                acc = __builtin_amdgcn_mfma_f32_16x16x32_bf16(a, bl8, acc, 0, 0, 0);
            }
            int dd = nd * 16 + l15, sbase = mq * 16 + quad * 4;
            float o[4];
            #pragma unroll
            for (int reg = 0; reg < 4; ++reg) {
                int qs = sbase + reg;
                o[reg] = (qs < 66) ? acc[reg] * inv[qs] : 0.f;   // zero K-pad
            }
            uint2 pk;
            pk.x = cvtpk(o[0], o[1]);
            pk.y = cvtpk(o[2], o[3]);
            *(uint2*)(smem + AOT_OFF + dd * 208 + 2 * sbase) = pk;
        }
        // zero aoT cols 80..103
        for (int u = tid; u < 384; u += 256) {
            int row = u / 12, kcol = 80 + 2 * (u % 12);
            *(unsigned*)(smem + AOT_OFF + row * 208 + 2 * kcol) = 0u;
        }
    }
    __syncthreads();

    // ---------------- Stage Wc hi/lo (overlays dead vT) ------------------------------
    if constexpr (MODE >= 1) {
        const unsigned char* wc = ws + WSWC_OFF;   // pre-built 13,312B image (zero-padded)
        for (int i = wid; i < 13; i += 4)
            gload16(wc + (i << 10) + (lane << 4), smem + WCH_OFF + (i << 10));
    } else {
        for (int u = tid; u < 726; u += 256) {           // 22 rows x 33 float2
            int row = u / 33, cp = u - row * 33;
            float2 w = *(const float2*)(Wc + row * 66 + 2 * cp);
            unsigned hi, lo;
            split2(w.x, w.y, hi, lo);
            *(unsigned*)(smem + WCH_OFF + row * 208 + 4 * cp) = hi;
            *(unsigned*)(smem + WCL_OFF + row * 208 + 4 * cp) = lo;
        }
        for (int u = tid; u < 836; u += 256) {           // zero cols 66..103, rows 0..21
            int comp = u >= 418 ? 1 : 0, rem = comp ? u - 418 : u;
            int row = rem / 19, kcol = 66 + 2 * (rem % 19);
            *(unsigned*)(smem + (comp ? WCL_OFF : WCH_OFF) + row * 208 + 2 * kcol) = 0u;
        }
    }
    __syncthreads();

    // ---------------- Phase 6: out = Wc @ ao + bc via MFMA ---------------------------
    {
        const short* Wch = (const short*)(smem + WCH_OFF);
        const short* Wcl = (const short*)(smem + WCL_OFF);
        const short* aoT = (const short*)(smem + AOT_OFF);
        int mj = wid >> 1, nd = wid & 1;
        f32x4 acc = (f32x4){0.f, 0.f, 0.f, 0.f};
        #pragma unroll
        for (int ks = 0; ks < 3; ++ks) {
            bf16x8 a   = *(const bf16x8*)(Wch + (mj * 16 + l15) * 104 + ks * 32 + quad * 8);
            bf16x8 al8 = *(const bf16x8*)(Wcl + (mj * 16 + l15) * 104 + ks * 32 + quad * 8);
            bf16x8 b   = *(const bf16x8*)(aoT + (nd * 16 + l15) * 104 + ks * 32 + quad * 8);
            acc = __builtin_amdgcn_mfma_f32_16x16x32_bf16(a, b, acc, 0, 0, 0);
            acc = __builtin_amdgcn_mfma_f32_16x16x32_bf16(al8, b, acc, 0, 0, 0);
        }
        int dd = nd * 16 + l15;
        #pragma unroll
        for (int reg = 0; reg < 4; ++reg) {
            int j = mj * 16 + quad * 4 + reg;
            if (j < 22) {
                size_t o = (size_t)(bt * J + j) * (H * D) + h * 32 + dd;
                out[o] = acc[reg] + bc[j];
            }
        }
    }
}

extern "C" void kernel_launch(void* const* d_in, const int* in_sizes, int n_in,
                              void* d_out, int out_size, void* d_ws, size_t ws_size,
                              hipStream_t stream) {
    const float* x  = (const float*)d_in[0];
    const float* Wq = (const float*)d_in[1];
    const float* bq = (const float*)d_in[2];
    const float* Wk = (const float*)d_in[3];
    const float* bk = (const float*)d_in[4];
    const float* Wv = (const float*)d_in[5];
    const float* bv = (const float*)d_in[6];
    const float* Wc = (const float*)d_in[7];
    const float* bc = (const float*)d_in[8];
    float* out = (float*)d_out;

    const int B = 512;
    dim3 grid(B * T * H), block(256);
    if (d_ws != nullptr && ws_size >= WS_FULL) {
        hipLaunchKernelGGL(presplit_kernel, dim3(199), dim3(256), 0, stream,
                           Wq, Wk, Wv, Wc, (unsigned char*)d_ws);
        hipLaunchKernelGGL(presplit_x_kernel, dim3(12288), dim3(256), 0, stream,
                           x, (unsigned char*)d_ws);
        hipLaunchKernelGGL((mha_fused_kernel<2>), grid, block, 0, stream,
                           x, Wq, bq, Wk, bk, Wv, bv, Wc, bc,
                           (const unsigned char*)d_ws, out);
    } else if (d_ws != nullptr && ws_size >= WS_W) {
        hipLaunchKernelGGL(presplit_kernel, dim3(199), dim3(256), 0, stream,
                           Wq, Wk, Wv, Wc, (unsigned char*)d_ws);
        hipLaunchKernelGGL((mha_fused_kernel<1>), grid, block, 0, stream,
                           x, Wq, bq, Wk, bk, Wv, bv, Wc, bc,
                           (const unsigned char*)d_ws, out);
    } else {
        hipLaunchKernelGGL((mha_fused_kernel<0>), grid, block, 0, stream,
                           x, Wq, bq, Wk, bk, Wv, bv, Wc, bc,
                           (const unsigned char*)nullptr, out);
    }
}

// Round 5
// 942.883 us; speedup vs baseline: 1.0765x; 1.0765x over previous
//
#include <hip/hip_runtime.h>
#include <hip/hip_bf16.h>

// R5 theory: R4 falsified "phase-1 LDS-bound" (conflicts bit-identical 2.173e7, dur flat).
// Bottleneck = attn-phase chain: sc LDS round-trip + softmax VALU + barriers @3 blocks/CU.
// 1) Fuse QK^T+softmax: per-wave row-block in regs, shfl-reduce on MFMA layout, sc deleted
//    (17.4KB LDS, 1 barrier, ~100 LDS ops/thread removed).
// 2) x-image rows 0..63 only (303->201MB); rows 64/65 direct from x; rows 66+ zeroed once.
// Predicted: main ~640us, pre ~180us, total ~820us, conflicts ~1.2e7, FETCH ~120MB.

constexpr int T  = 6;
constexpr int S  = 66;    // 3*J
constexpr int IN = 256;
constexpr int H  = 8;
constexpr int D  = 32;
constexpr int J  = 22;
constexpr float NEG = -9e15f;
constexpr float INV_SQRT_D = 0.17677669529663688110f; // 1/sqrt(32)

// ---------------- LDS map (bytes), SMEM 49,152 -> 3 blocks/CU ------------------------
// stage (per 64-K chunk): x m01 frag tiles [8 hi|8 lo]x1KB @0..16,384;
//   x m2 tiles (rows 64..95): hi @16,384, lo @20,480 (zero-init once; rows 64/65/chunk);
//   W frag tiles [12 hi|12 lo]x1KB @24,576..49,152.
// attn persistent: qh/ql [66][36] @0/4,752; kh/kl @9,504/14,256 (end 19,008);
//   vTh/vTl bf16[32][104] @27,456/34,112 (208B rows); inv f32[66] @40,768..41,032;
//   aoT bf16[32][104] @41,040..47,696.
// overlays: Ph/Pl bf16[66][104] @0/13,728 (after q/k dead); Wch/Wcl @27,456/34,112 (vT dead).
#define XM2H_OFF 16384
#define XM2L_OFF 20480
#define W_OFF    24576
#define W_LO     12288
#define QH_OFF   0
#define QL_OFF   4752
#define KH_OFF   9504
#define KL_OFF   14256
#define VTH_OFF  27456
#define VTL_OFF  34112
#define INV_OFF  40768
#define AOT_OFF  41040
#define PH_OFF   0
#define PL_OFF   13728
#define WCH_OFF  27456
#define WCL_OFF  34112
#define SMEM_BYTES 49152

// ws: 32 W images (h*4+chunk) of [12 hi|12 lo]x1KB = 24,576 -> 786,432;
// Wc image [hi 32x208B | lo 32x208B] = 13,312 -> 799,744;
// x images: per bt 4 chunks x 16,384 (rows 0..63 only) = 65,536 -> +201MB.
#define WSW_STRIDE 24576
#define WSWC_OFF   786432
#define WS_W       799744ull
#define XIMG_OFF   799744
#define XIMG_BT    65536
#define WS_FULL    (799744ull + 3072ull * 65536ull)

typedef float f32x4   __attribute__((ext_vector_type(4)));
typedef float f32x16  __attribute__((ext_vector_type(16)));
typedef short bf16x8  __attribute__((ext_vector_type(8)));
typedef short s4v     __attribute__((ext_vector_type(4)));

__device__ __forceinline__ unsigned cvtpk(float a, float b) {
    unsigned r;
    asm("v_cvt_pk_bf16_f32 %0, %1, %2" : "=v"(r) : "v"(a), "v"(b));
    return r;   // low16 = bf16(a), high16 = bf16(b), RNE
}
__device__ __forceinline__ float bfh2f(unsigned short h) {
    return __uint_as_float(((unsigned)h) << 16);
}
__device__ __forceinline__ void split2(float a, float b, unsigned& hi, unsigned& lo) {
    unsigned h = cvtpk(a, b);
    float ra = a - __uint_as_float(h << 16);
    float rb = b - __uint_as_float(h & 0xffff0000u);
    lo = cvtpk(ra, rb);
    hi = h;
}
__device__ __forceinline__ bf16x8 ld_bf16x8_a8(const short* p) {
    s4v a = *(const s4v*)p;
    s4v b = *(const s4v*)(p + 4);
    return __builtin_shufflevector(a, b, 0, 1, 2, 3, 4, 5, 6, 7);
}
__device__ __forceinline__ void gload16(const void* g, void* l) {
    __builtin_amdgcn_global_load_lds(
        (const __attribute__((address_space(1))) unsigned*)g,
        (__attribute__((address_space(3))) unsigned*)l, 16, 0, 0);
}

// ---------------- pre-kernel: W(h,chunk) fragment images + Wc image ------------------
__global__ __launch_bounds__(256)
void presplit_kernel(const float* __restrict__ Wq, const float* __restrict__ Wk,
                     const float* __restrict__ Wv, const float* __restrict__ Wc,
                     unsigned char* __restrict__ ws)
{
    int gid = blockIdx.x * 256 + threadIdx.x;
    if (gid < 49152) {                     // 32 images x 96 rows x 16 col-groups
        int img = gid / 1536, u = gid - img * 1536;
        int row = u >> 4, c = u & 15, k0 = c << 2;
        int mat = row >> 5, dd = row & 31;
        int chunk = img & 3, hh = img >> 2;
        const float* Wm = (mat == 0) ? Wq : (mat == 1) ? Wk : Wv;
        float4 v = *(const float4*)(Wm + (size_t)(hh * 32 + dd) * IN + chunk * 64 + c * 4);
        uint2 hi, lo;
        split2(v.x, v.y, hi.x, lo.x);
        split2(v.z, v.w, hi.y, lo.y);
        int tile  = (mat << 2) + (k0 >> 4);
        int lanei = dd + (((k0 >> 3) & 1) << 5);
        int byte  = (tile << 10) + (lanei << 4) + ((k0 & 7) << 1);
        unsigned char* base = ws + (size_t)img * WSW_STRIDE;
        *(uint2*)(base + byte)        = hi;
        *(uint2*)(base + W_LO + byte) = lo;
    } else if (gid < 49152 + 1664) {       // Wc image: 32 rows x 52 dword cols (zero-padded)
        int g2  = gid - 49152;
        int row = g2 / 52, cu = g2 - row * 52;
        int c0  = 2 * cu;
        float a = (row < 22 && c0     < 66) ? Wc[row * 66 + c0]     : 0.f;
        float b = (row < 22 && c0 + 1 < 66) ? Wc[row * 66 + c0 + 1] : 0.f;
        unsigned hi, lo;
        split2(a, b, hi, lo);
        *(unsigned*)(ws + WSWC_OFF + row * 208 + 4 * cu)        = hi;
        *(unsigned*)(ws + WSWC_OFF + 6656 + row * 208 + 4 * cu) = lo;
    }
}

// ---------------- pre-kernel: x rows 0..63 -> fragment-linear images -----------------
// One block per (bt, chunk): coalesced float4 reads -> swizzled LDS -> 16 x 1KB tiles
// as coalesced 16B stores. Rows 64/65 handled in main kernel; 66..95 zeroed there.
__global__ __launch_bounds__(256)
void presplit_x_kernel(const float* __restrict__ x, unsigned char* __restrict__ ws)
{
    __shared__ __align__(16) unsigned char lds[16384];
    const int tid = threadIdx.x;
    const int chunk = blockIdx.x & 3;
    const int bt = blockIdx.x >> 2;
    const float* xg = x + (size_t)bt * S * IN + chunk * 64;
    for (int u = tid; u < 1024; u += 256) {     // rows 0..63 x 16 col-groups
        int s = u >> 4, c = u & 15;
        int rel = ((s << 7) + (c << 3)) ^ ((s & 7) << 4);
        float4 v = *(const float4*)(xg + (size_t)s * IN + c * 4);
        uint2 hi, lo;
        split2(v.x, v.y, hi.x, lo.x);
        split2(v.z, v.w, hi.y, lo.y);
        *(uint2*)(lds + rel)        = hi;
        *(uint2*)(lds + 8192 + rel) = lo;
    }
    __syncthreads();
    const int lane = tid & 63, wid = tid >> 6;
    unsigned char* img = ws + XIMG_OFF + (size_t)bt * XIMG_BT + chunk * 16384;
    for (int i = wid; i < 16; i += 4) {
        int comp = (i >= 8) ? 1 : 0;
        int ti = i - comp * 8;
        int mtile = ti >> 2, ks = ti & 3;
        int row = mtile * 32 + (lane & 31);
        int rel = ((row << 7) + (ks << 5) + ((lane >> 5) << 4)) ^ ((row & 7) << 4);
        uint4 v = *(const uint4*)(lds + comp * 8192 + rel);
        *(uint4*)(img + (i << 10) + (lane << 4)) = v;
    }
}

// MODE: 0 = all inline, 1 = W/Wc presplit, 2 = W/Wc + x presplit
template<int MODE>
__global__ __launch_bounds__(256, 3)
void mha_fused_kernel(const float* __restrict__ x,
                      const float* __restrict__ Wq, const float* __restrict__ bq,
                      const float* __restrict__ Wk, const float* __restrict__ bk,
                      const float* __restrict__ Wv, const float* __restrict__ bv,
                      const float* __restrict__ Wc, const float* __restrict__ bc,
                      const unsigned char* __restrict__ ws,
                      float* __restrict__ out)
{
    __shared__ __align__(16) unsigned char smem[SMEM_BYTES];

    const int tid = threadIdx.x;
    // bt-grouping XCD swizzle: 8 heads of one bt land on one XCD, adjacent in time.
    const int i0  = blockIdx.x;
    const int h   = (i0 >> 3) & 7;
    const int bt  = (i0 & 7) | ((i0 >> 6) << 3);   // bijective over [0,3072)

    const int wid  = tid >> 6;           // wave 0..3
    const int lane = tid & 63;
    const int l15  = lane & 15;
    const int quad = lane >> 4;

    // zero x-m2 tiles once (rows 66..95 stay zero; rows 64/65 rewritten per chunk)
    for (int u = tid; u < 512; u += 256)
        *(uint4*)(smem + XM2H_OFF + u * 16) = (uint4){0u, 0u, 0u, 0u};

    // ---------------- Phase 1: q,k,v projections via split-bf16 32x32x16 MFMA --------
    const f32x16 zacc = {0.f,0.f,0.f,0.f,0.f,0.f,0.f,0.f,0.f,0.f,0.f,0.f,0.f,0.f,0.f,0.f};
    f32x16 accs[3] = {zacc, zacc, zacc};

    const float* xg0 = x + (size_t)bt * S * IN;
    for (int chunk = 0; chunk < 4; ++chunk) {    // K = 4 x 64
        __syncthreads();
        const float* xg = xg0 + chunk * 64;
        if constexpr (MODE == 2) {
            const unsigned char* ximg = ws + XIMG_OFF + (size_t)bt * XIMG_BT + chunk * 16384;
            const unsigned char* wimg = ws + (size_t)((h << 2) | chunk) * WSW_STRIDE;
            for (int i = wid; i < 16; i += 4)
                gload16(ximg + (i << 10) + (lane << 4), smem + (i << 10));
            for (int i = wid; i < 24; i += 4)
                gload16(wimg + (i << 10) + (lane << 4), smem + W_OFF + (i << 10));
            if (tid < 32) {                      // rows 64,65 direct from x (L2-hot)
                int s = 64 + (tid >> 4), c = tid & 15;
                float4 v = *(const float4*)(xg + (size_t)s * IN + c * 4);
                uint2 hi, lo;
                split2(v.x, v.y, hi.x, lo.x);
                split2(v.z, v.w, hi.y, lo.y);
                int off = ((c >> 2) << 10) + (((s & 31) + (((c >> 1) & 1) << 5)) << 4)
                        + ((c & 1) << 3);
                *(uint2*)(smem + XM2H_OFF + off) = hi;
                *(uint2*)(smem + XM2L_OFF + off) = lo;
            }
        } else {
            if constexpr (MODE == 1) {
                const unsigned char* wimg = ws + (size_t)((h << 2) | chunk) * WSW_STRIDE;
                for (int i = wid; i < 24; i += 4)
                    gload16(wimg + (i << 10) + (lane << 4), smem + W_OFF + (i << 10));
            } else {
                for (int u = tid; u < 1536; u += 256) {   // W inline -> fragment-linear
                    int row = u >> 4, c = u & 15, k0 = c << 2;
                    int mat = row >> 5, dd2 = row & 31;
                    const float* Wm = (mat == 0) ? Wq : (mat == 1) ? Wk : Wv;
                    float4 v = *(const float4*)(Wm + (size_t)(h * 32 + dd2) * IN + chunk * 64 + c * 4);
                    uint2 hi, lo;
                    split2(v.x, v.y, hi.x, lo.x);
                    split2(v.z, v.w, hi.y, lo.y);
                    int tile  = (mat << 2) + (k0 >> 4);
                    int lanei = dd2 + (((k0 >> 3) & 1) << 5);
                    int byte  = (tile << 10) + (lanei << 4) + ((k0 & 7) << 1);
                    *(uint2*)(smem + W_OFF + byte)        = hi;
                    *(uint2*)(smem + W_OFF + W_LO + byte) = lo;
                }
            }
            for (int u = tid; u < 1536; u += 256) {       // x inline (rows 0..95)
                int s = u >> 4, c = u & 15, k0 = c << 2;
                uint2 hi = {0u, 0u}, lo = {0u, 0u};
                if (s < 66) {
                    float4 v = *(const float4*)(xg + (size_t)s * IN + c * 4);
                    split2(v.x, v.y, hi.x, lo.x);
                    split2(v.z, v.w, hi.y, lo.y);
                }
                int ks = k0 >> 4, khalf = (k0 >> 3) & 1, b = (k0 & 7) << 1;
                int off = (ks << 10) + (((s & 31) + (khalf << 5)) << 4) + b;
                if (s < 64) {
                    int base = (s >> 5) * 4096 + off;
                    *(uint2*)(smem + base)        = hi;
                    *(uint2*)(smem + base + 8192) = lo;
                } else {
                    *(uint2*)(smem + XM2H_OFF + off) = hi;
                    *(uint2*)(smem + XM2L_OFF + off) = lo;
                }
            }
        }
        __syncthreads();

        #pragma unroll
        for (int t = 0; t < 3; ++t) {
            int p = wid + 4 * t;                 // p = mtile*3 + mat, over [0,9)
            if (p >= 9) break;                   // wave-uniform
            int mtile = p / 3, mat = p - mtile * 3;
            const unsigned char *xaH, *xaL;
            if (mtile < 2) { xaH = smem + ((mtile * 4) << 10) + (lane << 4); xaL = xaH + 8192; }
            else           { xaH = smem + XM2H_OFF + (lane << 4);            xaL = xaH + 4096; }
            const unsigned char* wbH = smem + W_OFF + ((mat * 4) << 10) + (lane << 4);
            #pragma unroll
            for (int ks = 0; ks < 4; ++ks) {
                bf16x8 ah = *(const bf16x8*)(xaH + (ks << 10));
                bf16x8 al = *(const bf16x8*)(xaL + (ks << 10));
                bf16x8 bh = *(const bf16x8*)(wbH + (ks << 10));
                bf16x8 bl = *(const bf16x8*)(wbH + (ks << 10) + W_LO);
                accs[t] = __builtin_amdgcn_mfma_f32_32x32x16_bf16(ah, bh, accs[t], 0, 0, 0);
                accs[t] = __builtin_amdgcn_mfma_f32_32x32x16_bf16(ah, bl, accs[t], 0, 0, 0);
                accs[t] = __builtin_amdgcn_mfma_f32_32x32x16_bf16(al, bh, accs[t], 0, 0, 0);
            }
        }
    }
    __syncthreads();   // stage dead; epilogue overwrites it

    // -------- Epilogue: q/k -> hi/lo [s][d]; v -> relu, hi/lo transposed [d][s] ------
    // 32x32 C/D layout: col = lane&31, row = (reg&3) + 8*(reg>>2) + 4*(lane>>5).
    {
        short* qh = (short*)(smem + QH_OFF); short* ql = (short*)(smem + QL_OFF);
        short* kh = (short*)(smem + KH_OFF); short* kl = (short*)(smem + KL_OFF);
        const int dd = lane & 31;
        const int half = lane >> 5;
        #pragma unroll
        for (int t = 0; t < 3; ++t) {
            int p = wid + 4 * t;
            if (p >= 9) break;
            int mtile = p / 3, mat = p - mtile * 3;
            const float* bias_p = (mat == 0) ? bq : (mat == 1) ? bk : bv;
            float bias = bias_p[h * 32 + dd];
            if (mat < 2) {
                short* bh_ = (mat == 0) ? qh : kh;
                short* bl_ = (mat == 0) ? ql : kl;
                #pragma unroll
                for (int g = 0; g < 4; ++g) {
                    int sb2 = mtile * 32 + half * 4 + 8 * g;
                    uint2 hi, lo;
                    split2(accs[t][4*g+0] + bias, accs[t][4*g+1] + bias, hi.x, lo.x);
                    split2(accs[t][4*g+2] + bias, accs[t][4*g+3] + bias, hi.y, lo.y);
                    unsigned hs[4] = { hi.x & 0xffffu, hi.x >> 16, hi.y & 0xffffu, hi.y >> 16 };
                    unsigned ls[4] = { lo.x & 0xffffu, lo.x >> 16, lo.y & 0xffffu, lo.y >> 16 };
                    #pragma unroll
                    for (int r = 0; r < 4; ++r) {
                        int s = sb2 + r;
                        if (s < 66) {
                            bh_[s * 36 + dd] = (short)hs[r];
                            bl_[s * 36 + dd] = (short)ls[r];
                        }
                    }
                }
            } else {
                #pragma unroll
                for (int g = 0; g < 4; ++g) {
                    int sb2 = mtile * 32 + half * 4 + 8 * g;
                    float vv[4];
                    #pragma unroll
                    for (int r = 0; r < 4; ++r) {
                        int s = sb2 + r;
                        vv[r] = (s < 66) ? fmaxf(accs[t][4*g+r] + bias, 0.f) : 0.f;
                    }
                    uint2 ph, pl;
                    split2(vv[0], vv[1], ph.x, pl.x);
                    split2(vv[2], vv[3], ph.y, pl.y);
                    *(uint2*)(smem + VTH_OFF + dd * 208 + 2 * sb2) = ph;
                    *(uint2*)(smem + VTL_OFF + dd * 208 + 2 * sb2) = pl;
                }
            }
        }
    }
    __syncthreads();

    // ------- Phase 3+4 fused: QK^T per-wave row-block, softmax in registers ----------
    // Wave w owns rows mq=w (wave 3 also mq=4). acc[mk][reg]: qs=mq*16+quad*4+reg,
    // ks=mk*16+l15. Row ops = in-lane over mk + shfl_xor over l15.
    {
        const short* qh = (const short*)(smem + QH_OFF);
        const short* ql = (const short*)(smem + QL_OFF);
        const short* kh = (const short*)(smem + KH_OFF);
        const short* kl = (const short*)(smem + KL_OFF);

        auto qk_mfma = [&](int mq, f32x4* acc) {
            int aoff = (mq * 16 + l15) * 36 + quad * 8;
            bf16x8 ah = ld_bf16x8_a8(qh + aoff);
            bf16x8 al = ld_bf16x8_a8(ql + aoff);
            #pragma unroll
            for (int mk = 0; mk < 5; ++mk) {
                int boff = (mk * 16 + l15) * 36 + quad * 8;
                bf16x8 bh = ld_bf16x8_a8(kh + boff);
                bf16x8 bl = ld_bf16x8_a8(kl + boff);
                f32x4 a = (f32x4){0.f, 0.f, 0.f, 0.f};
                a = __builtin_amdgcn_mfma_f32_16x16x32_bf16(ah, bh, a, 0, 0, 0);
                a = __builtin_amdgcn_mfma_f32_16x16x32_bf16(ah, bl, a, 0, 0, 0);
                a = __builtin_amdgcn_mfma_f32_16x16x32_bf16(al, bh, a, 0, 0, 0);
                acc[mk] = a;
            }
        };

        f32x4 accA[5], accB[5];
        qk_mfma(wid, accA);
        if (wid == 3) qk_mfma(4, accB);
        __syncthreads();   // all q/k reads done -> P may overlay q/k

        short* Ph = (short*)(smem + PH_OFF);
        short* Pl = (short*)(smem + PL_OFF);
        float* inv = (float*)(smem + INV_OFF);

        auto sm_store = [&](int mq, f32x4* acc) {
            float v[5][4];
            #pragma unroll
            for (int mk = 0; mk < 5; ++mk) {
                int ks = mk * 16 + l15;
                #pragma unroll
                for (int reg = 0; reg < 4; ++reg) {
                    int qs = mq * 16 + quad * 4 + reg;
                    bool invalid = (qs >= 66) || (ks >= 66);
                    bool masked = (qs < J && ks >= 2 * J) || (qs >= 2 * J && ks < J);
                    float s = acc[mk][reg] * INV_SQRT_D;
                    v[mk][reg] = invalid ? -INFINITY : (masked ? 0.f : s);
                }
            }
            float rmax[4];
            #pragma unroll
            for (int reg = 0; reg < 4; ++reg) {
                float mm = fmaxf(fmaxf(fmaxf(v[0][reg], v[1][reg]),
                                       fmaxf(v[2][reg], v[3][reg])), v[4][reg]);
                mm = fmaxf(mm, __shfl_xor(mm, 1));
                mm = fmaxf(mm, __shfl_xor(mm, 2));
                mm = fmaxf(mm, __shfl_xor(mm, 4));
                mm = fmaxf(mm, __shfl_xor(mm, 8));
                const float thr = mm / 9.0f;
                float rm = -INFINITY;
                #pragma unroll
                for (int mk = 0; mk < 5; ++mk) {
                    float sv = v[mk][reg];
                    float pr = (fabsf(sv) <= thr) ? NEG : sv;  // -INF sentinels stay below
                    v[mk][reg] = pr;
                    rm = fmaxf(rm, pr);
                }
                rm = fmaxf(rm, __shfl_xor(rm, 1));
                rm = fmaxf(rm, __shfl_xor(rm, 2));
                rm = fmaxf(rm, __shfl_xor(rm, 4));
                rm = fmaxf(rm, __shfl_xor(rm, 8));
                rmax[reg] = rm;
            }
            #pragma unroll
            for (int reg = 0; reg < 4; ++reg) {
                int qs = mq * 16 + quad * 4 + reg;
                float e[5], lsum = 0.f;
                #pragma unroll
                for (int mk = 0; mk < 5; ++mk) {
                    float ev = __expf(v[mk][reg] - rmax[reg]);  // -INF -> 0
                    e[mk] = ev;
                    lsum += ev;
                }
                lsum += __shfl_xor(lsum, 1);
                lsum += __shfl_xor(lsum, 2);
                lsum += __shfl_xor(lsum, 4);
                lsum += __shfl_xor(lsum, 8);
                if (qs < 66) {
                    #pragma unroll
                    for (int mk = 0; mk < 5; ++mk) {
                        int ks = mk * 16 + l15;
                        unsigned short hi = (unsigned short)cvtpk(e[mk], e[mk]);
                        unsigned short lo = (unsigned short)cvtpk(e[mk] - bfh2f(hi), 0.f);
                        Ph[qs * 104 + ks] = (short)hi;
                        Pl[qs * 104 + ks] = (short)lo;
                    }
                    if (l15 == 0) inv[qs] = 1.0f / lsum;
                }
            }
        };

        sm_store(wid, accA);
        if (wid == 3) sm_store(4, accB);

        // zero P cols 80..95 (rows 0..65): stale LDS there could be NaN-pattern bf16
        for (int u = tid; u < 264; u += 256) {
            int comp = u >= 132 ? 1 : 0, rem = u - comp * 132;
            int row = rem >> 1, part = rem & 1;
            *(uint4*)(smem + (comp ? PL_OFF : PH_OFF) + row * 208 + 160 + part * 16)
                = (uint4){0u, 0u, 0u, 0u};
        }
    }
    __syncthreads();

    // ---------------- Phase 5: aoT = (P @ v)^T * inv, bf16-hi, via MFMA --------------
    {
        const short* Ph = (const short*)(smem + PH_OFF);
        const short* Pl = (const short*)(smem + PL_OFF);
        const short* vh = (const short*)(smem + VTH_OFF);
        const short* vl = (const short*)(smem + VTL_OFF);
        const float* inv = (const float*)(smem + INV_OFF);
        for (int t = 0; t < 3; ++t) {
            int tt = wid + 4 * t;
            if (tt >= 10) break;
            int mq = tt >> 1, nd = tt & 1;
            f32x4 acc = (f32x4){0.f, 0.f, 0.f, 0.f};
            #pragma unroll
            for (int ks = 0; ks < 3; ++ks) {
                bf16x8 a   = *(const bf16x8*)(Ph + (mq * 16 + l15) * 104 + ks * 32 + quad * 8);
                bf16x8 al8 = *(const bf16x8*)(Pl + (mq * 16 + l15) * 104 + ks * 32 + quad * 8);
                bf16x8 b   = *(const bf16x8*)(vh + (nd * 16 + l15) * 104 + ks * 32 + quad * 8);
                bf16x8 bl8 = *(const bf16x8*)(vl + (nd * 16 + l15) * 104 + ks * 32 + quad * 8);
                acc = __builtin_amdgcn_mfma_f32_16x16x32_bf16(a, b, acc, 0, 0, 0);
                acc = __builtin_amdgcn_mfma_f32_16x16x32_bf16(al8, b, acc, 0, 0, 0);
                acc = __builtin_amdgcn_mfma_f32_16x16x32_bf16(a, bl8, acc, 0, 0, 0);
            }
            int dd = nd * 16 + l15, sbase = mq * 16 + quad * 4;
            float o[4];
            #pragma unroll
            for (int reg = 0; reg < 4; ++reg) {
                int qs = sbase + reg;
                o[reg] = (qs < 66) ? acc[reg] * inv[qs] : 0.f;
            }
            uint2 pk;
            pk.x = cvtpk(o[0], o[1]);
            pk.y = cvtpk(o[2], o[3]);
            *(uint2*)(smem + AOT_OFF + dd * 208 + 2 * sbase) = pk;
        }
        // zero aoT cols 80..103
        for (int u = tid; u < 384; u += 256) {
            int row = u / 12, kcol = 80 + 2 * (u % 12);
            *(unsigned*)(smem + AOT_OFF + row * 208 + 2 * kcol) = 0u;
        }
    }
    __syncthreads();

    // ---------------- Stage Wc hi/lo (overlays dead vT) ------------------------------
    if constexpr (MODE >= 1) {
        const unsigned char* wc = ws + WSWC_OFF;   // pre-built 13,312B image
        for (int i = wid; i < 13; i += 4)
            gload16(wc + (i << 10) + (lane << 4), smem + WCH_OFF + (i << 10));
    } else {
        for (int u = tid; u < 726; u += 256) {           // 22 rows x 33 float2
            int row = u / 33, cp = u - row * 33;
            float2 w = *(const float2*)(Wc + row * 66 + 2 * cp);
            unsigned hi, lo;
            split2(w.x, w.y, hi, lo);
            *(unsigned*)(smem + WCH_OFF + row * 208 + 4 * cp) = hi;
            *(unsigned*)(smem + WCL_OFF + row * 208 + 4 * cp) = lo;
        }
        for (int u = tid; u < 836; u += 256) {           // zero cols 66..103, rows 0..21
            int comp = u >= 418 ? 1 : 0, rem = comp ? u - 418 : u;
            int row = rem / 19, kcol = 66 + 2 * (rem % 19);
            *(unsigned*)(smem + (comp ? WCL_OFF : WCH_OFF) + row * 208 + 2 * kcol) = 0u;
        }
    }
    __syncthreads();

    // ---------------- Phase 6: out = Wc @ ao + bc via MFMA ---------------------------
    {
        const short* Wch = (const short*)(smem + WCH_OFF);
        const short* Wcl = (const short*)(smem + WCL_OFF);
        const short* aoT = (const short*)(smem + AOT_OFF);
        int mj = wid >> 1, nd = wid & 1;
        f32x4 acc = (f32x4){0.f, 0.f, 0.f, 0.f};
        #pragma unroll
        for (int ks = 0; ks < 3; ++ks) {
            bf16x8 a   = *(const bf16x8*)(Wch + (mj * 16 + l15) * 104 + ks * 32 + quad * 8);
            bf16x8 al8 = *(const bf16x8*)(Wcl + (mj * 16 + l15) * 104 + ks * 32 + quad * 8);
            bf16x8 b   = *(const bf16x8*)(aoT + (nd * 16 + l15) * 104 + ks * 32 + quad * 8);
            acc = __builtin_amdgcn_mfma_f32_16x16x32_bf16(a, b, acc, 0, 0, 0);
            acc = __builtin_amdgcn_mfma_f32_16x16x32_bf16(al8, b, acc, 0, 0, 0);
        }
        int dd = nd * 16 + l15;
        #pragma unroll
        for (int reg = 0; reg < 4; ++reg) {
            int j = mj * 16 + quad * 4 + reg;
            if (j < 22) {
                size_t o = (size_t)(bt * J + j) * (H * D) + h * 32 + dd;
                out[o] = acc[reg] + bc[j];
            }
        }
    }
}

extern "C" void kernel_launch(void* const* d_in, const int* in_sizes, int n_in,
                              void* d_out, int out_size, void* d_ws, size_t ws_size,
                              hipStream_t stream) {
    const float* x  = (const float*)d_in[0];
    const float* Wq = (const float*)d_in[1];
    const float* bq = (const float*)d_in[2];
    const float* Wk = (const float*)d_in[3];
    const float* bk = (const float*)d_in[4];
    const float* Wv = (const float*)d_in[5];
    const float* bv = (const float*)d_in[6];
    const float* Wc = (const float*)d_in[7];
    const float* bc = (const float*)d_in[8];
    float* out = (float*)d_out;

    const int B = 512;
    dim3 grid(B * T * H), block(256);
    if (d_ws != nullptr && ws_size >= WS_FULL) {
        hipLaunchKernelGGL(presplit_kernel, dim3(199), dim3(256), 0, stream,
                           Wq, Wk, Wv, Wc, (unsigned char*)d_ws);
        hipLaunchKernelGGL(presplit_x_kernel, dim3(12288), dim3(256), 0, stream,
                           x, (unsigned char*)d_ws);
        hipLaunchKernelGGL((mha_fused_kernel<2>), grid, block, 0, stream,
                           x, Wq, bq, Wk, bk, Wv, bv, Wc, bc,
                           (const unsigned char*)d_ws, out);
    } else if (d_ws != nullptr && ws_size >= WS_W) {
        hipLaunchKernelGGL(presplit_kernel, dim3(199), dim3(256), 0, stream,
                           Wq, Wk, Wv, Wc, (unsigned char*)d_ws);
        hipLaunchKernelGGL((mha_fused_kernel<1>), grid, block, 0, stream,
                           x, Wq, bq, Wk, bk, Wv, bv, Wc, bc,
                           (const unsigned char*)d_ws, out);
    } else {
        hipLaunchKernelGGL((mha_fused_kernel<0>), grid, block, 0, stream,
                           x, Wq, bq, Wk, bk, Wv, bv, Wc, bc,
                           (const unsigned char*)nullptr, out);
    }
}